// Round 5
// baseline (235.525 us; speedup 1.0000x reference)
//
#include <hip/hip_runtime.h>
#include <cstdint>
#include <cstddef>

#define B_  64
#define D_  128
#define LC_ 1024
#define LQ_ 128
#define NEGV (-1e30f)
#define NINF (-3.402823466e38f)

typedef short s16x8 __attribute__((ext_vector_type(8)));
typedef float f32x4 __attribute__((ext_vector_type(4)));

__device__ __forceinline__ unsigned short f2bf(float x) {
    union { float f; unsigned u; } v; v.f = x;
    unsigned r = v.u + 0x7fffu + ((v.u >> 16) & 1u);   // RNE
    return (unsigned short)(r >> 16);
}
__device__ __forceinline__ float bf2f(unsigned short u) {
    union { unsigned u; float f; } v; v.u = ((unsigned)u) << 16; return v.f;
}

// ---------------------------------------------------------------------------
// k1: per (b, 128-c-tile) block, 256 thr, 2 blocks/CU:
//   - redundant Q[b] transpose -> QT LDS [q][d] bf16 (+ sq_l local)
//   - stage C -> CW [d][c] bf16*wm (XOR-swizzled), sc partials  (C read ONCE)
//   - S-MFMA (A from CW transposed-gather, B from QT LDS)
//   - softmax row stats + col partial stats (pmax/psum -> global)
//   - Tg -> QT region; S1 packed in regs across T2-GEMM
//   - T2 partial GEMM: A = CW (C*wm bf16, ds_read_b64 pairs), B = Tg;
//     epilogue scales by 1/wm[d]; partials stored bf16 [q][d] (ushort4)
//   - S1 -> CW -> S1b global (coalesced)
// grid (LC/128, B)
// ---------------------------------------------------------------------------
__global__ __launch_bounds__(256, 2) void k1(const float* __restrict__ C,
                                             const float* __restrict__ Q,
                                             const float* __restrict__ cmask,
                                             const float* __restrict__ qmask,
                                             const float* __restrict__ w,
                                             unsigned short* __restrict__ S1b,
                                             float* __restrict__ pmax_g,
                                             float* __restrict__ psum_g,
                                             unsigned short* __restrict__ T2pb) {
    __shared__ unsigned short CW[128 * 136];   // Q fp32 scratch -> [d][c] bf16*wm -> S1 [c][q]
    __shared__ unsigned short QT[128 * 136];   // Qt [q][d] bf16 -> later Tg [q][c]
    __shared__ float4 red4[8][32];             // wq_l (fp32[128]) first, then sc partials
    __shared__ float wc_l[128], wm_l[128], rwm_l[128], cmv_l[128], qmv_l[128], sc_l[128], sq_l[128];

    int t = threadIdx.x;
    int b = blockIdx.y, ct = blockIdx.x, c0 = ct * 128;
    int g = t >> 5, c4 = t & 31;

    // ---- issue all 16 C-tile loads up front (hidden under Q phase) ----
    float4 v[16];
    {
        const float4* Cb = (const float4*)(C + (size_t)b * D_ * LC_ + c0);
#pragma unroll
        for (int j = 0; j < 16; j++) {
            int d = j * 8 + g;
            v[j] = Cb[(size_t)d * (LC_ / 4) + c4];
        }
    }
    float* wq_l = (float*)red4;
    if (t < 128) {
        float wmv = w[2 * D_ + t];
        wq_l[t] = w[t];
        wc_l[t] = w[D_ + t];
        wm_l[t] = wmv;
        rwm_l[t] = (wmv != 0.0f) ? (1.0f / wmv) : 0.0f;
        cmv_l[t] = (1.0f - cmask[b * LC_ + c0 + t]) * NEGV;
        qmv_l[t] = (1.0f - qmask[b * LQ_ + t]) * NEGV;
    }
    __syncthreads();

    // ---- Q[b] transpose -> QT [q][136] bf16; sq_l = sum_d Q*wq ----
    {
        float* CWf = (float*)CW;               // [64][132] fp32 scratch
        int qq = t >> 1, ph = t & 1;
        float sqv = 0.f;
#pragma unroll
        for (int h = 0; h < 2; h++) {
#pragma unroll
            for (int j = 0; j < 8; j++) {
                int idx = j * 256 + t;
                int r = idx >> 5, cc = idx & 31;
                float4 qv = *(const float4*)&Q[((size_t)(b * D_ + h * 64 + r)) * LQ_ + cc * 4];
                *(float4*)&CWf[r * 132 + cc * 4] = qv;
            }
            __syncthreads();
            unsigned short u[32];
#pragma unroll
            for (int k = 0; k < 32; k++) {
                float val = CWf[(ph * 32 + k) * 132 + qq];
                sqv += val * wq_l[h * 64 + ph * 32 + k];
                u[k] = f2bf(val);
            }
#pragma unroll
            for (int k4 = 0; k4 < 8; k4++) {
                ushort4 o;
                o.x = u[k4 * 4 + 0]; o.y = u[k4 * 4 + 1];
                o.z = u[k4 * 4 + 2]; o.w = u[k4 * 4 + 3];
                *(ushort4*)&QT[qq * 136 + h * 64 + ph * 32 + k4 * 4] = o;
            }
            __syncthreads();
        }
        sqv += __shfl_xor(sqv, 1, 64);
        if (ph == 0) sq_l[qq] = sqv;
    }

    // ---- convert + stage C -> CW [d][c] with 8B-block XOR swizzle; sc ----
    {
        float4 scp = {0.f, 0.f, 0.f, 0.f};
#pragma unroll
        for (int j = 0; j < 16; j++) {
            int d = j * 8 + g;
            float wcv = wc_l[d], wmv = wm_l[d];
            scp.x += v[j].x * wcv;
            scp.y += v[j].y * wcv;
            scp.z += v[j].z * wcv;
            scp.w += v[j].w * wcv;
            ushort4 o;
            o.x = f2bf(v[j].x * wmv);
            o.y = f2bf(v[j].y * wmv);
            o.z = f2bf(v[j].z * wmv);
            o.w = f2bf(v[j].w * wmv);
            *(ushort4*)&CW[d * 136 + ((c4 ^ (j & 7)) << 2)] = o;   // (d>>3)&7 == j&7
        }
        red4[g][c4] = scp;
    }
    __syncthreads();
    if (t < 128) {
        float s = 0.f;
#pragma unroll
        for (int gg = 0; gg < 8; gg++) {
            const float* rp = (const float*)&red4[gg][t >> 2];
            s += rp[t & 3];
        }
        sc_l[t] = s;
    }
    __syncthreads();

    // ---- S-MFMA: A gathered transposed from swizzled CW, B from QT LDS ----
    int wv = t >> 6, l = t & 63, quad = l >> 4, lp = l & 15;
    int w32 = wv * 32;
    f32x4 zero = {0.f, 0.f, 0.f, 0.f};
    f32x4 acc[2][8];
#pragma unroll
    for (int mc = 0; mc < 2; mc++)
#pragma unroll
        for (int qt = 0; qt < 8; qt++) acc[mc][qt] = zero;

#pragma unroll
    for (int ks = 0; ks < 4; ks++) {
        s16x8 a[2], bb[8];
        int x3 = (ks * 4 + quad) & 7;
#pragma unroll
        for (int mc = 0; mc < 2; mc++) {
            s16x8 av;
            int c = w32 + mc * 16 + lp;
            int cb = ((c >> 2) ^ x3) << 2, clo = c & 3;
#pragma unroll
            for (int e = 0; e < 8; e++)
                av[e] = (short)CW[(ks * 32 + quad * 8 + e) * 136 + cb + clo];
            a[mc] = av;
        }
#pragma unroll
        for (int qt = 0; qt < 8; qt++)
            bb[qt] = *(const s16x8*)&QT[(qt * 16 + lp) * 136 + ks * 32 + quad * 8];
#pragma unroll
        for (int mc = 0; mc < 2; mc++)
#pragma unroll
            for (int qt = 0; qt < 8; qt++)
                acc[mc][qt] = __builtin_amdgcn_mfma_f32_16x16x32_bf16(a[mc], bb[qt], acc[mc][qt], 0, 0, 0);
    }
#pragma unroll
    for (int mc = 0; mc < 2; mc++)
#pragma unroll
        for (int qt = 0; qt < 8; qt++)
#pragma unroll
            for (int i = 0; i < 4; i++)
                acc[mc][qt][i] += sc_l[w32 + mc * 16 + quad * 4 + i] + sq_l[qt * 16 + lp];

    float qmv_r[8];
#pragma unroll
    for (int qt = 0; qt < 8; qt++) qmv_r[qt] = qmv_l[qt * 16 + lp];
    float cmv_r[2][4];
#pragma unroll
    for (int mc = 0; mc < 2; mc++)
#pragma unroll
        for (int i = 0; i < 4; i++) cmv_r[mc][i] = cmv_l[w32 + mc * 16 + quad * 4 + i];

    // ---- (1) row max ----
    float rm_r[2][4];
#pragma unroll
    for (int mc = 0; mc < 2; mc++)
#pragma unroll
        for (int i = 0; i < 4; i++) {
            float m = NINF;
#pragma unroll
            for (int qt = 0; qt < 8; qt++) m = fmaxf(m, acc[mc][qt][i] + qmv_r[qt]);
#pragma unroll
            for (int off = 1; off < 16; off <<= 1) m = fmaxf(m, __shfl_xor(m, off, 64));
            rm_r[mc][i] = m;
        }

    // ---- (2) col partial stats from raw S ----
    int chunk = ct * 4 + wv;
#pragma unroll
    for (int qt = 0; qt < 8; qt++) {
        float cm = NINF;
#pragma unroll
        for (int mc = 0; mc < 2; mc++)
#pragma unroll
            for (int i = 0; i < 4; i++) cm = fmaxf(cm, acc[mc][qt][i] + cmv_r[mc][i]);
        cm = fmaxf(cm, __shfl_xor(cm, 16, 64));
        cm = fmaxf(cm, __shfl_xor(cm, 32, 64));
        float cs = 0.f;
#pragma unroll
        for (int mc = 0; mc < 2; mc++)
#pragma unroll
            for (int i = 0; i < 4; i++) cs += __expf(acc[mc][qt][i] + cmv_r[mc][i] - cm);
        cs += __shfl_xor(cs, 16, 64);
        cs += __shfl_xor(cs, 32, 64);
        if (l < 16) {
            pmax_g[((size_t)(b * 32 + chunk)) * LQ_ + qt * 16 + lp] = cm;
            psum_g[((size_t)(b * 32 + chunk)) * LQ_ + qt * 16 + lp] = cs;
        }
    }

    // ---- (3) exp-overwrite acc + (4) row sum / ri / gs ----
    float ri_r[2][4], gs_r[2][4];
#pragma unroll
    for (int mc = 0; mc < 2; mc++)
#pragma unroll
        for (int i = 0; i < 4; i++) {
            float s = 0.f;
#pragma unroll
            for (int qt = 0; qt < 8; qt++) {
                float e = __expf(acc[mc][qt][i] + qmv_r[qt] - rm_r[mc][i]);
                acc[mc][qt][i] = e;
                s += e;
            }
#pragma unroll
            for (int off = 1; off < 16; off <<= 1) s += __shfl_xor(s, off, 64);
            ri_r[mc][i] = 1.0f / s;
            gs_r[mc][i] = s * __expf(rm_r[mc][i] + cmv_r[mc][i]);
        }

    // ---- (5) Tg -> QT region; S1 packed into registers (CW stays = C*wm) ----
    unsigned s1pk[2][8][2];
    __syncthreads();   // all S-MFMA reads of CW/QT done
#pragma unroll
    for (int mc = 0; mc < 2; mc++)
#pragma unroll
        for (int qt = 0; qt < 8; qt++) {
            unsigned short u[4];
#pragma unroll
            for (int i = 0; i < 4; i++) {
                int row = w32 + mc * 16 + quad * 4 + i;
                int q = qt * 16 + lp;
                float s1 = acc[mc][qt][i] * ri_r[mc][i];
                u[i] = f2bf(s1);
                QT[q * 136 + row] = f2bf(s1 * gs_r[mc][i]);
            }
            s1pk[mc][qt][0] = (unsigned)u[0] | ((unsigned)u[1] << 16);
            s1pk[mc][qt][1] = (unsigned)u[2] | ((unsigned)u[3] << 16);
        }
    __syncthreads();   // Tg ready; CW still holds C*wm

    // ---- T2 partial GEMM: A = CW (C*wm bf16, b64 pairs), B = Tg ----
    f32x4 acc2[2][8];
#pragma unroll
    for (int mc = 0; mc < 2; mc++)
#pragma unroll
        for (int nt = 0; nt < 8; nt++) acc2[mc][nt] = zero;
#pragma unroll
    for (int ks = 0; ks < 4; ks++) {
        s16x8 a2[2], bb[8];
#pragma unroll
        for (int m = 0; m < 2; m++) {
            int d = w32 + m * 16 + lp;
            int xd = (d >> 3) & 7;
            int cg = ks * 8 + quad * 2;
            union { s16x8 vv; uint2 u2[2]; } A;
            A.u2[0] = *(const uint2*)&CW[d * 136 + ((cg ^ xd) << 2)];
            A.u2[1] = *(const uint2*)&CW[d * 136 + (((cg + 1) ^ xd) << 2)];
            a2[m] = A.vv;
        }
#pragma unroll
        for (int nt = 0; nt < 8; nt++)
            bb[nt] = *(const s16x8*)&QT[(nt * 16 + lp) * 136 + ks * 32 + quad * 8];
#pragma unroll
        for (int m = 0; m < 2; m++)
#pragma unroll
            for (int nt = 0; nt < 8; nt++)
                acc2[m][nt] = __builtin_amdgcn_mfma_f32_16x16x32_bf16(a2[m], bb[nt], acc2[m][nt], 0, 0, 0);
    }
    // T2 partial store: bf16, [q][d] layout, scaled by 1/wm[d]
    {
        size_t baseq = ((size_t)(ct * B_ + b)) * LQ_;
#pragma unroll
        for (int mc = 0; mc < 2; mc++) {
            int d0 = w32 + mc * 16 + quad * 4;
            float r0 = rwm_l[d0], r1 = rwm_l[d0 + 1], r2 = rwm_l[d0 + 2], r3 = rwm_l[d0 + 3];
#pragma unroll
            for (int nt = 0; nt < 8; nt++) {
                int q = nt * 16 + lp;
                ushort4 o;
                o.x = f2bf(acc2[mc][nt][0] * r0);
                o.y = f2bf(acc2[mc][nt][1] * r1);
                o.z = f2bf(acc2[mc][nt][2] * r2);
                o.w = f2bf(acc2[mc][nt][3] * r3);
                *(ushort4*)&T2pb[(baseq + q) * D_ + d0] = o;
            }
        }
    }

    // ---- S1 -> CW [c][q]; then coalesced copy-out ----
    __syncthreads();   // all T2 A-reads of CW done
#pragma unroll
    for (int mc = 0; mc < 2; mc++)
#pragma unroll
        for (int qt = 0; qt < 8; qt++) {
            int row0 = w32 + mc * 16 + quad * 4;
            int q = qt * 16 + lp;
            CW[(row0 + 0) * 136 + q] = (unsigned short)(s1pk[mc][qt][0] & 0xffffu);
            CW[(row0 + 1) * 136 + q] = (unsigned short)(s1pk[mc][qt][0] >> 16);
            CW[(row0 + 2) * 136 + q] = (unsigned short)(s1pk[mc][qt][1] & 0xffffu);
            CW[(row0 + 3) * 136 + q] = (unsigned short)(s1pk[mc][qt][1] >> 16);
        }
    __syncthreads();
    {
        int row = t >> 1, qh = (t & 1) * 64;
        const uint4* src = (const uint4*)&CW[row * 136 + qh];
        uint4* dst = (uint4*)&S1b[((size_t)(b * LC_ + c0 + row)) * LQ_ + qh];
#pragma unroll
        for (int j = 0; j < 8; j++) dst[j] = src[j];
    }
}

// ---------------------------------------------------------------------------
// k2: per (b, d-chunk of 16): softmax-2 scale (redundant, L2-hot) +
//     T2pb 8-tile reduce ([q][d] bf16) -> LDS transpose -> T2b [d][q] bf16
// grid (B*8), 256 thr
// ---------------------------------------------------------------------------
__global__ __launch_bounds__(256) void k2(const float* __restrict__ pmax_g,
                                          const float* __restrict__ psum_g,
                                          const unsigned short* __restrict__ T2pb,
                                          unsigned short* __restrict__ T2b) {
    __shared__ float scale_l[128];
    __shared__ float trans[16][132];
    int t = threadIdx.x;
    int bid = blockIdx.x;
    int b = bid >> 3, dc = bid & 7;
    if (t < 128) {
        float m = NINF;
        for (int j = 0; j < 32; j++)
            m = fmaxf(m, pmax_g[((size_t)(b * 32 + j)) * LQ_ + t]);
        float s = 0.f;
        for (int j = 0; j < 32; j++)
            s += psum_g[((size_t)(b * 32 + j)) * LQ_ + t] *
                 __expf(pmax_g[((size_t)(b * 32 + j)) * LQ_ + t] - m);
        scale_l[t] = __expf(-m) / s;
    }
    __syncthreads();
    {
        int q = t >> 1, dh = t & 1;
        float a8[8] = {0.f, 0.f, 0.f, 0.f, 0.f, 0.f, 0.f, 0.f};
#pragma unroll
        for (int j = 0; j < 8; j++) {
            const ushort4* p = (const ushort4*)&T2pb[(((size_t)j * B_ + b) * LQ_ + q) * D_ + dc * 16 + dh * 8];
            ushort4 x0 = p[0], x1 = p[1];
            a8[0] += bf2f(x0.x); a8[1] += bf2f(x0.y); a8[2] += bf2f(x0.z); a8[3] += bf2f(x0.w);
            a8[4] += bf2f(x1.x); a8[5] += bf2f(x1.y); a8[6] += bf2f(x1.z); a8[7] += bf2f(x1.w);
        }
        float sc = scale_l[q];
#pragma unroll
        for (int k = 0; k < 8; k++) trans[dh * 8 + k][q] = a8[k] * sc;
    }
    __syncthreads();
    {
        int dl = t >> 4, q8 = (t & 15) * 8;
        f32x4 v0 = *(const f32x4*)&trans[dl][q8];
        f32x4 v1 = *(const f32x4*)&trans[dl][q8 + 4];
        ushort4 o0, o1;
        o0.x = f2bf(v0[0]); o0.y = f2bf(v0[1]); o0.z = f2bf(v0[2]); o0.w = f2bf(v0[3]);
        o1.x = f2bf(v1[0]); o1.y = f2bf(v1[1]); o1.z = f2bf(v1[2]); o1.w = f2bf(v1[3]);
        size_t tb = ((size_t)(b * D_ + dc * 16 + dl)) * LQ_ + q8;
        *(ushort4*)&T2b[tb] = o0;
        *(ushort4*)&T2b[tb + 4] = o1;
    }
}

// ---------------------------------------------------------------------------
// k3: output GEMMs. A-fragments: Q fp32 direct-convert + T2b bf16;
//     B-fragments: S1b global. Epilogue: C re-read + 4-stream NT stores.
// grid (LC/128, B), 256 thr
// ---------------------------------------------------------------------------
__global__ __launch_bounds__(256) void k3(const float* __restrict__ C,
                                          const float* __restrict__ Q,
                                          const unsigned short* __restrict__ T2b,
                                          const unsigned short* __restrict__ S1b,
                                          float* __restrict__ out) {
    int t = threadIdx.x;
    int b = blockIdx.y, c0 = blockIdx.x * 128;
    int wv = t >> 6, l = t & 63, quad = l >> 4, lp = l & 15;
    int w32 = wv * 32;
    f32x4 zero = {0.f, 0.f, 0.f, 0.f};
    f32x4 accA[2][8], accB[2][8];
#pragma unroll
    for (int mc = 0; mc < 2; mc++)
#pragma unroll
        for (int nt = 0; nt < 8; nt++) { accA[mc][nt] = zero; accB[mc][nt] = zero; }

#pragma unroll
    for (int ks = 0; ks < 4; ks++) {
        s16x8 aq[2], at[2], bb[8];
#pragma unroll
        for (int mc = 0; mc < 2; mc++) {
            int d = w32 + mc * 16 + lp;
            const float4* p = (const float4*)&Q[((size_t)(b * D_ + d)) * LQ_ + ks * 32 + quad * 8];
            float4 v0 = p[0], v1 = p[1];
            unsigned short* pp = (unsigned short*)&aq[mc];
            pp[0] = f2bf(v0.x); pp[1] = f2bf(v0.y); pp[2] = f2bf(v0.z); pp[3] = f2bf(v0.w);
            pp[4] = f2bf(v1.x); pp[5] = f2bf(v1.y); pp[6] = f2bf(v1.z); pp[7] = f2bf(v1.w);
            at[mc] = *(const s16x8*)&T2b[((size_t)(b * D_ + d)) * LQ_ + ks * 32 + quad * 8];
        }
#pragma unroll
        for (int nt = 0; nt < 8; nt++)
            bb[nt] = *(const s16x8*)&S1b[((size_t)(b * LC_ + c0 + nt * 16 + lp)) * LQ_ + ks * 32 + quad * 8];
#pragma unroll
        for (int mc = 0; mc < 2; mc++)
#pragma unroll
            for (int nt = 0; nt < 8; nt++) {
                accA[mc][nt] = __builtin_amdgcn_mfma_f32_16x16x32_bf16(aq[mc], bb[nt], accA[mc][nt], 0, 0, 0);
                accB[mc][nt] = __builtin_amdgcn_mfma_f32_16x16x32_bf16(at[mc], bb[nt], accB[mc][nt], 0, 0, 0);
            }
    }
    const size_t DL = (size_t)D_ * LC_;
#pragma unroll
    for (int mc = 0; mc < 2; mc++)
#pragma unroll
        for (int i = 0; i < 4; i++) {
            int d = w32 + mc * 16 + quad * 4 + i;
            const float* Crow = C + ((size_t)(b * D_ + d)) * LC_ + c0;
            size_t ob = ((size_t)(b * 4 * D_ + d)) * LC_ + c0;
#pragma unroll
            for (int nt = 0; nt < 8; nt++) {
                int c = nt * 16 + lp;
                float cv = Crow[c];
                float a = accA[mc][nt][i];
                float bt = accB[mc][nt][i];
                __builtin_nontemporal_store(cv, &out[ob + c]);
                __builtin_nontemporal_store(a, &out[ob + DL + c]);
                __builtin_nontemporal_store(cv * a, &out[ob + 2 * DL + c]);
                __builtin_nontemporal_store(cv * bt, &out[ob + 3 * DL + c]);
            }
        }
}

// ---------------------------------------------------------------------------
extern "C" void kernel_launch(void* const* d_in, const int* in_sizes, int n_in,
                              void* d_out, int out_size, void* d_ws, size_t ws_size,
                              hipStream_t stream) {
    const float* C     = (const float*)d_in[0];
    const float* Q     = (const float*)d_in[1];
    const float* cmask = (const float*)d_in[2];
    const float* qmask = (const float*)d_in[3];
    const float* w     = (const float*)d_in[4];
    float* out = (float*)d_out;

    unsigned short* us = (unsigned short*)d_ws;
    unsigned short* S1b  = us;                                  // B*LC*LQ
    unsigned short* T2b  = S1b + (size_t)B_ * LC_ * LQ_;        // B*D*LQ
    unsigned short* T2pb = T2b + (size_t)B_ * D_ * LQ_;         // 8*B*LQ*D (bf16, [q][d])
    float* fp = (float*)(T2pb + (size_t)8 * B_ * D_ * LQ_);
    float* pmax_g = fp;                                         // B*32*LQ
    float* psum_g = pmax_g + (size_t)B_ * 32 * LQ_;             // B*32*LQ

    k1<<<dim3(LC_ / 128, B_), 256, 0, stream>>>(C, Q, cmask, qmask, w,
                                                S1b, pmax_g, psum_g, T2pb);
    k2<<<dim3(B_ * 8), 256, 0, stream>>>(pmax_g, psum_g, T2pb, T2b);
    k3<<<dim3(LC_ / 128, B_), 256, 0, stream>>>(C, Q, T2b, S1b, out);
}

// Round 6
// 215.456 us; speedup vs baseline: 1.0931x; 1.0931x over previous
//
#include <hip/hip_runtime.h>
#include <cstdint>
#include <cstddef>

#define B_  64
#define D_  128
#define LC_ 1024
#define LQ_ 128
#define NEGV (-1e30f)
#define NINF (-3.402823466e38f)

typedef short s16x8 __attribute__((ext_vector_type(8)));
typedef float f32x4 __attribute__((ext_vector_type(4)));

__device__ __forceinline__ unsigned short f2bf(float x) {
    union { float f; unsigned u; } v; v.f = x;
    unsigned r = v.u + 0x7fffu + ((v.u >> 16) & 1u);   // RNE
    return (unsigned short)(r >> 16);
}
__device__ __forceinline__ float bf2f(unsigned short u) {
    union { unsigned u; float f; } v; v.u = ((unsigned)u) << 16; return v.f;
}

// ---------------------------------------------------------------------------
// k1: per (b, 128-c-tile) block, 256 thr, 2 blocks/CU  (== round-4 k1, except
//     T2 partials stored bf16 instead of fp32; same [d][q] layout/indexing):
//   - redundant Q[b] transpose -> QT LDS [q][d] bf16 (+ sq_l local)
//   - stage C -> CW [d][c] bf16*wm (XOR-swizzled), sc partials
//   - S-MFMA (A from CW transposed-gather, B from QT LDS)
//   - softmax row stats + col partial stats (pmax/psum -> global)
//   - S1 -> S1b global; S1*g -> Tg LDS (QT region reused)
//   - T2 partial GEMM -> T2pb global (bf16)
// grid (LC/128, B)
// ---------------------------------------------------------------------------
__global__ __launch_bounds__(256, 2) void k1(const float* __restrict__ C,
                                             const float* __restrict__ Q,
                                             const float* __restrict__ cmask,
                                             const float* __restrict__ qmask,
                                             const float* __restrict__ w,
                                             unsigned short* __restrict__ S1b,
                                             float* __restrict__ pmax_g,
                                             float* __restrict__ psum_g,
                                             unsigned short* __restrict__ T2pb) {
    __shared__ unsigned short CW[128 * 136];   // Q-stage fp32 scratch -> [d][c] bf16*wm -> S1 [c][q]
    __shared__ unsigned short QT[128 * 136];   // Qt [q][d] bf16 -> later Tg [q][c]
    __shared__ float4 red4[8][32];             // wq_l (fp32[128]) first, then sc partials
    __shared__ float wc_l[128], wm_l[128], cmv_l[128], qmv_l[128], sc_l[128], sq_l[128];

    int t = threadIdx.x;
    int b = blockIdx.y, ct = blockIdx.x, c0 = ct * 128;
    int g = t >> 5, c4 = t & 31;

    // ---- issue all 16 C-tile loads up front (hidden under Q phase) ----
    float4 v[16];
    {
        const float4* Cb = (const float4*)(C + (size_t)b * D_ * LC_ + c0);
#pragma unroll
        for (int j = 0; j < 16; j++) {
            int d = j * 8 + g;
            v[j] = Cb[(size_t)d * (LC_ / 4) + c4];
        }
    }
    float* wq_l = (float*)red4;
    if (t < 128) {
        wq_l[t] = w[t];
        wc_l[t] = w[D_ + t];
        wm_l[t] = w[2 * D_ + t];
        cmv_l[t] = (1.0f - cmask[b * LC_ + c0 + t]) * NEGV;
        qmv_l[t] = (1.0f - qmask[b * LQ_ + t]) * NEGV;
    }
    __syncthreads();

    // ---- Q[b] transpose -> QT [q][136] bf16; sq_l = sum_d Q*wq ----
    {
        float* CWf = (float*)CW;               // [64][132] fp32 scratch
        int qq = t >> 1, ph = t & 1;
        float sqv = 0.f;
#pragma unroll
        for (int h = 0; h < 2; h++) {
#pragma unroll
            for (int j = 0; j < 8; j++) {
                int idx = j * 256 + t;
                int r = idx >> 5, cc = idx & 31;
                float4 qv = *(const float4*)&Q[((size_t)(b * D_ + h * 64 + r)) * LQ_ + cc * 4];
                *(float4*)&CWf[r * 132 + cc * 4] = qv;
            }
            __syncthreads();
            unsigned short u[32];
#pragma unroll
            for (int k = 0; k < 32; k++) {
                float val = CWf[(ph * 32 + k) * 132 + qq];
                sqv += val * wq_l[h * 64 + ph * 32 + k];
                u[k] = f2bf(val);
            }
#pragma unroll
            for (int k4 = 0; k4 < 8; k4++) {
                ushort4 o;
                o.x = u[k4 * 4 + 0]; o.y = u[k4 * 4 + 1];
                o.z = u[k4 * 4 + 2]; o.w = u[k4 * 4 + 3];
                *(ushort4*)&QT[qq * 136 + h * 64 + ph * 32 + k4 * 4] = o;
            }
            __syncthreads();
        }
        sqv += __shfl_xor(sqv, 1, 64);
        if (ph == 0) sq_l[qq] = sqv;
    }

    // ---- convert + stage C -> CW [d][c] with 8B-block XOR swizzle; sc ----
    {
        float4 scp = {0.f, 0.f, 0.f, 0.f};
#pragma unroll
        for (int j = 0; j < 16; j++) {
            int d = j * 8 + g;
            float wcv = wc_l[d], wmv = wm_l[d];
            scp.x += v[j].x * wcv;
            scp.y += v[j].y * wcv;
            scp.z += v[j].z * wcv;
            scp.w += v[j].w * wcv;
            ushort4 o;
            o.x = f2bf(v[j].x * wmv);
            o.y = f2bf(v[j].y * wmv);
            o.z = f2bf(v[j].z * wmv);
            o.w = f2bf(v[j].w * wmv);
            *(ushort4*)&CW[d * 136 + ((c4 ^ (j & 7)) << 2)] = o;   // (d>>3)&7 == j&7
        }
        red4[g][c4] = scp;
    }
    __syncthreads();
    if (t < 128) {
        float s = 0.f;
#pragma unroll
        for (int gg = 0; gg < 8; gg++) {
            const float* rp = (const float*)&red4[gg][t >> 2];
            s += rp[t & 3];
        }
        sc_l[t] = s;
    }
    __syncthreads();

    // ---- S-MFMA: A gathered transposed from swizzled CW, B from QT LDS ----
    int wv = t >> 6, l = t & 63, quad = l >> 4, lp = l & 15;
    int w32 = wv * 32;
    f32x4 zero = {0.f, 0.f, 0.f, 0.f};
    f32x4 acc[2][8];
#pragma unroll
    for (int mc = 0; mc < 2; mc++)
#pragma unroll
        for (int qt = 0; qt < 8; qt++) acc[mc][qt] = zero;

#pragma unroll
    for (int ks = 0; ks < 4; ks++) {
        s16x8 a[2], bb[8];
        int x3 = (ks * 4 + quad) & 7;
#pragma unroll
        for (int mc = 0; mc < 2; mc++) {
            s16x8 av;
            int c = w32 + mc * 16 + lp;
            int cb = ((c >> 2) ^ x3) << 2, clo = c & 3;
#pragma unroll
            for (int e = 0; e < 8; e++)
                av[e] = (short)CW[(ks * 32 + quad * 8 + e) * 136 + cb + clo];
            a[mc] = av;
        }
#pragma unroll
        for (int qt = 0; qt < 8; qt++)
            bb[qt] = *(const s16x8*)&QT[(qt * 16 + lp) * 136 + ks * 32 + quad * 8];
#pragma unroll
        for (int mc = 0; mc < 2; mc++)
#pragma unroll
            for (int qt = 0; qt < 8; qt++)
                acc[mc][qt] = __builtin_amdgcn_mfma_f32_16x16x32_bf16(a[mc], bb[qt], acc[mc][qt], 0, 0, 0);
    }
#pragma unroll
    for (int mc = 0; mc < 2; mc++)
#pragma unroll
        for (int qt = 0; qt < 8; qt++)
#pragma unroll
            for (int i = 0; i < 4; i++)
                acc[mc][qt][i] += sc_l[w32 + mc * 16 + quad * 4 + i] + sq_l[qt * 16 + lp];

    float qmv_r[8];
#pragma unroll
    for (int qt = 0; qt < 8; qt++) qmv_r[qt] = qmv_l[qt * 16 + lp];
    float cmv_r[2][4];
#pragma unroll
    for (int mc = 0; mc < 2; mc++)
#pragma unroll
        for (int i = 0; i < 4; i++) cmv_r[mc][i] = cmv_l[w32 + mc * 16 + quad * 4 + i];

    // ---- (1) row max ----
    float rm_r[2][4];
#pragma unroll
    for (int mc = 0; mc < 2; mc++)
#pragma unroll
        for (int i = 0; i < 4; i++) {
            float m = NINF;
#pragma unroll
            for (int qt = 0; qt < 8; qt++) m = fmaxf(m, acc[mc][qt][i] + qmv_r[qt]);
#pragma unroll
            for (int off = 1; off < 16; off <<= 1) m = fmaxf(m, __shfl_xor(m, off, 64));
            rm_r[mc][i] = m;
        }

    // ---- (2) col partial stats from raw S ----
    int chunk = ct * 4 + wv;
#pragma unroll
    for (int qt = 0; qt < 8; qt++) {
        float cm = NINF;
#pragma unroll
        for (int mc = 0; mc < 2; mc++)
#pragma unroll
            for (int i = 0; i < 4; i++) cm = fmaxf(cm, acc[mc][qt][i] + cmv_r[mc][i]);
        cm = fmaxf(cm, __shfl_xor(cm, 16, 64));
        cm = fmaxf(cm, __shfl_xor(cm, 32, 64));
        float cs = 0.f;
#pragma unroll
        for (int mc = 0; mc < 2; mc++)
#pragma unroll
            for (int i = 0; i < 4; i++) cs += __expf(acc[mc][qt][i] + cmv_r[mc][i] - cm);
        cs += __shfl_xor(cs, 16, 64);
        cs += __shfl_xor(cs, 32, 64);
        if (l < 16) {
            pmax_g[((size_t)(b * 32 + chunk)) * LQ_ + qt * 16 + lp] = cm;
            psum_g[((size_t)(b * 32 + chunk)) * LQ_ + qt * 16 + lp] = cs;
        }
    }

    // ---- (3) exp-overwrite acc + (4) row sum / ri / gs ----
    float ri_r[2][4], gs_r[2][4];
#pragma unroll
    for (int mc = 0; mc < 2; mc++)
#pragma unroll
        for (int i = 0; i < 4; i++) {
            float s = 0.f;
#pragma unroll
            for (int qt = 0; qt < 8; qt++) {
                float e = __expf(acc[mc][qt][i] + qmv_r[qt] - rm_r[mc][i]);
                acc[mc][qt][i] = e;
                s += e;
            }
#pragma unroll
            for (int off = 1; off < 16; off <<= 1) s += __shfl_xor(s, off, 64);
            ri_r[mc][i] = 1.0f / s;
            gs_r[mc][i] = s * __expf(rm_r[mc][i] + cmv_r[mc][i]);
        }

    // ---- (5) S1 -> CW [c][q] plain; S1*g -> Tg (QT region) [q][c] ----
    __syncthreads();   // all CW/QT fragment reads done
#pragma unroll
    for (int mc = 0; mc < 2; mc++)
#pragma unroll
        for (int qt = 0; qt < 8; qt++)
#pragma unroll
            for (int i = 0; i < 4; i++) {
                int row = w32 + mc * 16 + quad * 4 + i;
                int q = qt * 16 + lp;
                float s1 = acc[mc][qt][i] * ri_r[mc][i];
                CW[row * 136 + q] = f2bf(s1);
                QT[q * 136 + row] = f2bf(s1 * gs_r[mc][i]);
            }
    __syncthreads();

    // ---- S1b copy-out (coalesced) ----
    {
        int row = t >> 1, qh = (t & 1) * 64;
        const uint4* src = (const uint4*)&CW[row * 136 + qh];
        uint4* dst = (uint4*)&S1b[((size_t)(b * LC_ + c0 + row)) * LQ_ + qh];
#pragma unroll
        for (int j = 0; j < 8; j++) dst[j] = src[j];
    }

    // ---- T2 partial GEMM: A = C (fp32->bf16, L2-hot re-read), B = Tg ----
    f32x4 acc2[2][8];
#pragma unroll
    for (int mc = 0; mc < 2; mc++)
#pragma unroll
        for (int nt = 0; nt < 8; nt++) acc2[mc][nt] = zero;
#pragma unroll
    for (int ks = 0; ks < 4; ks++) {
        s16x8 a2[2], bb[8];
#pragma unroll
        for (int m = 0; m < 2; m++) {
            int d = w32 + m * 16 + lp;
            const float4* p = (const float4*)&C[((size_t)(b * D_ + d)) * LC_ + c0 + ks * 32 + quad * 8];
            float4 v0 = p[0], v1 = p[1];
            unsigned short* pp = (unsigned short*)&a2[m];
            pp[0] = f2bf(v0.x); pp[1] = f2bf(v0.y); pp[2] = f2bf(v0.z); pp[3] = f2bf(v0.w);
            pp[4] = f2bf(v1.x); pp[5] = f2bf(v1.y); pp[6] = f2bf(v1.z); pp[7] = f2bf(v1.w);
        }
#pragma unroll
        for (int nt = 0; nt < 8; nt++)
            bb[nt] = *(const s16x8*)&QT[(nt * 16 + lp) * 136 + ks * 32 + quad * 8];
#pragma unroll
        for (int m = 0; m < 2; m++)
#pragma unroll
            for (int nt = 0; nt < 8; nt++)
                acc2[m][nt] = __builtin_amdgcn_mfma_f32_16x16x32_bf16(a2[m], bb[nt], acc2[m][nt], 0, 0, 0);
    }
    // bf16 partial store, same [d][q] layout/indexing as round-4 (coalesced in q)
    size_t base = ((size_t)(ct * B_ + b)) * ((size_t)D_ * LQ_);
#pragma unroll
    for (int mc = 0; mc < 2; mc++)
#pragma unroll
        for (int i = 0; i < 4; i++) {
            int d = w32 + mc * 16 + quad * 4 + i;
#pragma unroll
            for (int nt = 0; nt < 8; nt++)
                T2pb[base + (size_t)d * LQ_ + nt * 16 + lp] = f2bf(acc2[mc][nt][i]);
        }
}

// ---------------------------------------------------------------------------
// k2: per (b, d-chunk of 16): softmax-2 scale (redundant, L2-hot) +
//     T2pb 8-tile reduce (bf16 [d][q]) -> T2b bf16.  grid (B*8), 256 thr
// ---------------------------------------------------------------------------
__global__ __launch_bounds__(256) void k2(const float* __restrict__ pmax_g,
                                          const float* __restrict__ psum_g,
                                          const unsigned short* __restrict__ T2pb,
                                          unsigned short* __restrict__ T2b) {
    __shared__ float scale_l[128];
    int t = threadIdx.x;
    int bid = blockIdx.x;
    int b = bid >> 3, dc = bid & 7;
    if (t < 128) {
        float m = NINF;
        for (int j = 0; j < 32; j++)
            m = fmaxf(m, pmax_g[((size_t)(b * 32 + j)) * LQ_ + t]);
        float s = 0.f;
        for (int j = 0; j < 32; j++)
            s += psum_g[((size_t)(b * 32 + j)) * LQ_ + t] *
                 __expf(pmax_g[((size_t)(b * 32 + j)) * LQ_ + t] - m);
        scale_l[t] = __expf(-m) / s;
    }
    __syncthreads();
    int d = dc * 16 + (t >> 4), q8 = (t & 15) * 8;
    float a8[8] = {0.f, 0.f, 0.f, 0.f, 0.f, 0.f, 0.f, 0.f};
#pragma unroll
    for (int j = 0; j < 8; j++) {
        const ushort4* p = (const ushort4*)&T2pb[(((size_t)j * B_ + b) * D_ + d) * LQ_ + q8];
        ushort4 x0 = p[0], x1 = p[1];
        a8[0] += bf2f(x0.x); a8[1] += bf2f(x0.y); a8[2] += bf2f(x0.z); a8[3] += bf2f(x0.w);
        a8[4] += bf2f(x1.x); a8[5] += bf2f(x1.y); a8[6] += bf2f(x1.z); a8[7] += bf2f(x1.w);
    }
    ushort4 o0, o1;
    o0.x = f2bf(a8[0] * scale_l[q8 + 0]);
    o0.y = f2bf(a8[1] * scale_l[q8 + 1]);
    o0.z = f2bf(a8[2] * scale_l[q8 + 2]);
    o0.w = f2bf(a8[3] * scale_l[q8 + 3]);
    o1.x = f2bf(a8[4] * scale_l[q8 + 4]);
    o1.y = f2bf(a8[5] * scale_l[q8 + 5]);
    o1.z = f2bf(a8[6] * scale_l[q8 + 6]);
    o1.w = f2bf(a8[7] * scale_l[q8 + 7]);
    size_t tb = ((size_t)(b * D_ + d)) * LQ_ + q8;
    *(ushort4*)&T2b[tb] = o0;
    *(ushort4*)&T2b[tb + 4] = o1;
}

// ---------------------------------------------------------------------------
// k3: output GEMMs. A-fragments: Q fp32 direct-convert + T2b bf16;
//     B-fragments: S1b global.  Epilogue: C re-read + 4-stream stores.
// grid (LC/128, B), 256 thr   (== round-4 k3, unchanged)
// ---------------------------------------------------------------------------
__global__ __launch_bounds__(256) void k3(const float* __restrict__ C,
                                          const float* __restrict__ Q,
                                          const unsigned short* __restrict__ T2b,
                                          const unsigned short* __restrict__ S1b,
                                          float* __restrict__ out) {
    int t = threadIdx.x;
    int b = blockIdx.y, c0 = blockIdx.x * 128;
    int wv = t >> 6, l = t & 63, quad = l >> 4, lp = l & 15;
    int w32 = wv * 32;
    f32x4 zero = {0.f, 0.f, 0.f, 0.f};
    f32x4 accA[2][8], accB[2][8];
#pragma unroll
    for (int mc = 0; mc < 2; mc++)
#pragma unroll
        for (int nt = 0; nt < 8; nt++) { accA[mc][nt] = zero; accB[mc][nt] = zero; }

#pragma unroll
    for (int ks = 0; ks < 4; ks++) {
        s16x8 aq[2], at[2], bb[8];
#pragma unroll
        for (int mc = 0; mc < 2; mc++) {
            int d = w32 + mc * 16 + lp;
            const float4* p = (const float4*)&Q[((size_t)(b * D_ + d)) * LQ_ + ks * 32 + quad * 8];
            float4 v0 = p[0], v1 = p[1];
            unsigned short* pp = (unsigned short*)&aq[mc];
            pp[0] = f2bf(v0.x); pp[1] = f2bf(v0.y); pp[2] = f2bf(v0.z); pp[3] = f2bf(v0.w);
            pp[4] = f2bf(v1.x); pp[5] = f2bf(v1.y); pp[6] = f2bf(v1.z); pp[7] = f2bf(v1.w);
            at[mc] = *(const s16x8*)&T2b[((size_t)(b * D_ + d)) * LQ_ + ks * 32 + quad * 8];
        }
#pragma unroll
        for (int nt = 0; nt < 8; nt++)
            bb[nt] = *(const s16x8*)&S1b[((size_t)(b * LC_ + c0 + nt * 16 + lp)) * LQ_ + ks * 32 + quad * 8];
#pragma unroll
        for (int mc = 0; mc < 2; mc++)
#pragma unroll
            for (int nt = 0; nt < 8; nt++) {
                accA[mc][nt] = __builtin_amdgcn_mfma_f32_16x16x32_bf16(aq[mc], bb[nt], accA[mc][nt], 0, 0, 0);
                accB[mc][nt] = __builtin_amdgcn_mfma_f32_16x16x32_bf16(at[mc], bb[nt], accB[mc][nt], 0, 0, 0);
            }
    }
    const size_t DL = (size_t)D_ * LC_;
#pragma unroll
    for (int mc = 0; mc < 2; mc++)
#pragma unroll
        for (int i = 0; i < 4; i++) {
            int d = w32 + mc * 16 + quad * 4 + i;
            const float* Crow = C + ((size_t)(b * D_ + d)) * LC_ + c0;
            size_t ob = ((size_t)(b * 4 * D_ + d)) * LC_ + c0;
#pragma unroll
            for (int nt = 0; nt < 8; nt++) {
                int c = nt * 16 + lp;
                float cv = Crow[c];
                float a = accA[mc][nt][i];
                float bt = accB[mc][nt][i];
                out[ob + c] = cv;
                out[ob + DL + c] = a;
                out[ob + 2 * DL + c] = cv * a;
                out[ob + 3 * DL + c] = cv * bt;
            }
        }
}

// ---------------------------------------------------------------------------
extern "C" void kernel_launch(void* const* d_in, const int* in_sizes, int n_in,
                              void* d_out, int out_size, void* d_ws, size_t ws_size,
                              hipStream_t stream) {
    const float* C     = (const float*)d_in[0];
    const float* Q     = (const float*)d_in[1];
    const float* cmask = (const float*)d_in[2];
    const float* qmask = (const float*)d_in[3];
    const float* w     = (const float*)d_in[4];
    float* out = (float*)d_out;

    unsigned short* us = (unsigned short*)d_ws;
    unsigned short* S1b  = us;                                  // B*LC*LQ
    unsigned short* T2b  = S1b + (size_t)B_ * LC_ * LQ_;        // B*D*LQ
    unsigned short* T2pb = T2b + (size_t)B_ * D_ * LQ_;         // 8*B*D*LQ (bf16, [d][q])
    float* fp = (float*)(T2pb + (size_t)8 * B_ * D_ * LQ_);
    float* pmax_g = fp;                                         // B*32*LQ
    float* psum_g = pmax_g + (size_t)B_ * 32 * LQ_;             // B*32*LQ

    k1<<<dim3(LC_ / 128, B_), 256, 0, stream>>>(C, Q, cmask, qmask, w,
                                                S1b, pmax_g, psum_g, T2pb);
    k2<<<dim3(B_ * 8), 256, 0, stream>>>(pmax_g, psum_g, T2pb, T2b);
    k3<<<dim3(LC_ / 128, B_), 256, 0, stream>>>(C, Q, T2b, S1b, out);
}